// Round 11
// baseline (1725.180 us; speedup 1.0000x reference)
//
#include <hip/hip_runtime.h>
#include <hip/hip_bf16.h>

// Problem dims
#define BB 16
#define SS 512
#define IN_ 128
#define DD 512
#define HH 512
#define DA 30
#define RR 10
#define G3 1536   // 3*H

// ---- ws layout (bytes) ----
constexpr size_t OFF_H    = 0;                        // tagged h ring u32[2][16][512]: 65,536
constexpr size_t OFF_DF   = 131072;                   // dtype flag: 256
constexpr size_t OFF_CX   = OFF_DF   + 256;           // canonical fp32 inputs
constexpr size_t OFF_CW0  = OFF_CX   + 4194304;
constexpr size_t OFF_CB0  = OFF_CW0  + 262144;
constexpr size_t OFF_CW1  = OFF_CB0  + 2048;
constexpr size_t OFF_CB1  = OFF_CW1  + 61440;
constexpr size_t OFF_CW2  = OFF_CB1  + 256;
constexpr size_t OFF_CB2  = OFF_CW2  + 2048;
constexpr size_t OFF_CWIH = OFF_CB2  + 256;
constexpr size_t OFF_CWHH = OFF_CWIH + 3145728;
constexpr size_t OFF_CBI  = OFF_CWHH + 3145728;
constexpr size_t OFF_CBH  = OFF_CBI  + 6144;
constexpr size_t OFF_WT   = OFF_CBH  + 6144;          // W_hh^T bf16 [1536][512]
constexpr size_t OFF_WIHT = OFF_WT   + 1572864;       // W_ih^T bf16 [1536][512]
constexpr size_t OFF_W0T  = OFF_WIHT + 1572864;       // W0^T bf16 [512][128]
constexpr size_t OFF_MM   = OFF_W0T  + 131072;        // M bf16 [8192][512]
constexpr size_t OFF_BIG  = OFF_MM   + 8388608;
constexpr size_t OFF_M    = OFF_BIG;                  // m bf16 [8192][512]
constexpr size_t OFF_E    = OFF_BIG  + 8388608;       // e f32 [8192][10]
constexpr size_t OFF_INV  = OFF_E    + 327680;        // inv f32
constexpr size_t OFF_GI   = OFF_BIG;                  // gi aliases m/e/inv (dead after k_attn)
constexpr size_t NEED_GI32 = OFF_BIG + 50331648;      // gi fp32 path total

typedef __attribute__((ext_vector_type(8))) short bf16x8;
typedef __attribute__((ext_vector_type(4))) float f32x4;

__device__ __forceinline__ float bflo(unsigned int u) { return __uint_as_float(u << 16); }
__device__ __forceinline__ float bfhi(unsigned int u) { return __uint_as_float(u & 0xffff0000u); }
__device__ __forceinline__ float bf1(unsigned short u) { return __uint_as_float(((unsigned int)u) << 16); }
__device__ __forceinline__ unsigned short f2b(float f) {
  __hip_bfloat16 h = __float2bfloat16(f);
  return *(unsigned short*)&h;
}

__device__ __forceinline__ float ldgi(const float* p) { return *p; }
__device__ __forceinline__ float ldgi(const __hip_bfloat16* p) { return __bfloat162float(*p); }
__device__ __forceinline__ void stgi(float* p, float v) { *p = v; }
__device__ __forceinline__ void stgi(__hip_bfloat16* p, float v) { *p = __float2bfloat16(v); }

// ---------------- K0a: detect input dtype + zero the h ring ----------------
__global__ __launch_bounds__(256) void k_detect(const unsigned short* __restrict__ xs,
                                                int* __restrict__ dflag,
                                                uint4* __restrict__ hz) {
  const int tid = threadIdx.x;
  // zero tagged h ring: 65,536 B = 4096 uint4 (bits 0 == h=0.0 with tag 0)
  const uint4 z = {0u, 0u, 0u, 0u};
  #pragma unroll
  for (int i = 0; i < 16; i++) hz[tid + i * 256] = z;
  int bad = 0;
  for (int i = tid; i < 8192; i += 256) {
    const float v = bf1(xs[i]);
    if (!(fabsf(v) < 1.0e3f)) bad++;   // NaN also counts
  }
  __shared__ int s;
  if (tid == 0) s = 0;
  __syncthreads();
  atomicAdd(&s, bad);
  __syncthreads();
  if (tid == 0) dflag[0] = (s > 16) ? 1 : 0;   // 1 = fp32 buffers, 0 = bf16 buffers
}

// ---------------- K0b: canonicalize all inputs to fp32 ----------------
struct CvtArgs { const void* src[11]; float* dst[11]; int n[11]; };
__global__ __launch_bounds__(256) void k_cvt(CvtArgs a, const int* __restrict__ dflag) {
  const int ai = blockIdx.y;
  const int n = a.n[ai];
  const int stride = gridDim.x * blockDim.x;
  const int f32 = dflag[0];
  float* dst = a.dst[ai];
  if (f32) {
    const float* src = (const float*)a.src[ai];
    for (int i = blockIdx.x * blockDim.x + threadIdx.x; i < n; i += stride) dst[i] = src[i];
  } else {
    const unsigned short* src = (const unsigned short*)a.src[ai];
    for (int i = blockIdx.x * blockDim.x + threadIdx.x; i < n; i += stride) dst[i] = bf1(src[i]);
  }
}

// ---------------- K1: fused transpose of W_hh, W_ih (512x1536) and W0 (128x512) ------
__global__ __launch_bounds__(1024) void k_transpose3(const float* __restrict__ Whh,
    const float* __restrict__ Wih, const float* __restrict__ W0,
    __hip_bfloat16* __restrict__ WhhT, __hip_bfloat16* __restrict__ WihT,
    __hip_bfloat16* __restrict__ W0T) {
  __shared__ float tile[32][33];
  int id = blockIdx.x;
  const float* W; __hip_bfloat16* WT; int R, C, tx, ty;
  if (id < 768)       { W = Whh; WT = WhhT; R = DD;  C = G3; tx = id % 48; ty = id / 48; }
  else if (id < 1536) { id -= 768;  W = Wih; WT = WihT; R = DD;  C = G3; tx = id % 48; ty = id / 48; }
  else                { id -= 1536; W = W0;  WT = W0T;  R = IN_; C = DD; tx = id % 16; ty = id / 16; }
  const int c0 = tx * 32, k0 = ty * 32;
  tile[threadIdx.y][threadIdx.x] = W[(k0 + threadIdx.y) * C + c0 + threadIdx.x];
  __syncthreads();
  WT[(c0 + threadIdx.y) * R + k0 + threadIdx.x] = __float2bfloat16(tile[threadIdx.x][threadIdx.y]);
}

// ---------------- K5: unified MFMA GEMM: C[M][N] = A[M][KD] @ Bt[N][KD]^T + bias ------
// Tile 128x128, 4 waves (2x2 of 64x64), BK=32. A staged fp32->bf16 or bf16 direct.
// C/D frag: col=lane&15, row=quad*4+reg (m89-verified).
template<typename AT, typename GT, int KD, bool RELU>
__global__ __launch_bounds__(256) void k_gemm(const AT* __restrict__ A,
    const __hip_bfloat16* __restrict__ Bt, const float* __restrict__ bias,
    GT* __restrict__ C, int ldc) {
  __shared__ short As[128 * 40];   // 128 rows x 32 k, stride 40 (bank de-phase)
  __shared__ short Bs[128 * 40];
  const int tid = threadIdx.x;
  const int bn = blockIdx.x * 128, bm = blockIdx.y * 128;
  const int lane = tid & 63, w = tid >> 6;
  const int wm = (w >> 1) * 64, wn = (w & 1) * 64;
  const int l15 = lane & 15, quad = lane >> 4;
  const int srow = tid >> 1, shalf = tid & 1;    // staging: row, 16-elem half of 32-chunk
  f32x4 acc[4][4];
  #pragma unroll
  for (int i = 0; i < 4; i++)
    #pragma unroll
    for (int j = 0; j < 4; j++) acc[i][j] = (f32x4){0.f, 0.f, 0.f, 0.f};
  const uint4* Bg = (const uint4*)(Bt + (size_t)(bn + srow) * KD);
  short* Asd = &As[srow * 40 + shalf * 16];
  short* Bsd = &Bs[srow * 40 + shalf * 16];
  #pragma unroll 2
  for (int kc = 0; kc < KD / 32; kc++) {
    if constexpr (sizeof(AT) == 4) {   // fp32 A: 16 floats -> 16 bf16
      const float4* Agf = (const float4*)(A + (size_t)(bm + srow) * KD) + kc * 8 + shalf * 4;
      const float4 f0 = Agf[0], f1 = Agf[1], f2 = Agf[2], f3 = Agf[3];
      unsigned short t16[16] = {
        f2b(f0.x), f2b(f0.y), f2b(f0.z), f2b(f0.w),
        f2b(f1.x), f2b(f1.y), f2b(f1.z), f2b(f1.w),
        f2b(f2.x), f2b(f2.y), f2b(f2.z), f2b(f2.w),
        f2b(f3.x), f2b(f3.y), f2b(f3.z), f2b(f3.w)};
      *(uint4*)&Asd[0] = *(uint4*)&t16[0];
      *(uint4*)&Asd[8] = *(uint4*)&t16[8];
    } else {                            // bf16 A
      const uint4* Ag = (const uint4*)(A + (size_t)(bm + srow) * KD);
      const uint4 a0 = Ag[kc * 4 + shalf * 2], a1 = Ag[kc * 4 + shalf * 2 + 1];
      *(uint4*)&Asd[0] = a0; *(uint4*)&Asd[8] = a1;
    }
    const uint4 b0 = Bg[kc * 4 + shalf * 2], b1 = Bg[kc * 4 + shalf * 2 + 1];
    *(uint4*)&Bsd[0] = b0; *(uint4*)&Bsd[8] = b1;
    __syncthreads();
    bf16x8 af[4], bf[4];
    #pragma unroll
    for (int tt = 0; tt < 4; tt++) {
      af[tt] = *(const bf16x8*)&As[(wm + tt * 16 + l15) * 40 + quad * 8];
      bf[tt] = *(const bf16x8*)&Bs[(wn + tt * 16 + l15) * 40 + quad * 8];
    }
    #pragma unroll
    for (int tm = 0; tm < 4; tm++)
      #pragma unroll
      for (int tn = 0; tn < 4; tn++)
        acc[tm][tn] = __builtin_amdgcn_mfma_f32_16x16x32_bf16(af[tm], bf[tn], acc[tm][tn], 0, 0, 0);
    __syncthreads();
  }
  #pragma unroll
  for (int tn = 0; tn < 4; tn++) {
    const int col = bn + wn + tn * 16 + l15;
    const float bv = bias[col];
    #pragma unroll
    for (int tm = 0; tm < 4; tm++) {
      const int row = bm + wm + tm * 16 + quad * 4;
      #pragma unroll
      for (int i = 0; i < 4; i++) {
        float v = acc[tm][tn][i] + bv;
        if constexpr (RELU) v = fmaxf(v, 0.f);
        stgi(C + (size_t)(row + i) * ldc + col, v);
      }
    }
  }
}

// ---------------- K2b: scores per row: e = exp(tanh(m@W1+b1)@W2+b2) ----------------
__global__ __launch_bounds__(256) void k_scores(const __hip_bfloat16* __restrict__ m,
    const float* __restrict__ W1, const float* __restrict__ b1,
    const float* __restrict__ W2, const float* __restrict__ b2,
    float* __restrict__ e) {
  const int row = blockIdx.x;        // b*512+s
  const int tid = threadIdx.x;       // 256
  __shared__ float ms[DD];
  __shared__ float as[DA];
  __shared__ float part[8][32];
  {
    const unsigned int mm = ((const unsigned int*)(m + (size_t)row * DD))[tid];
    ms[2 * tid] = bflo(mm); ms[2 * tid + 1] = bfhi(mm);
  }
  __syncthreads();
  // m@W1: seg-split over k — all 256 threads active (a2<30 lanes idle only)
  const int a2 = tid & 31, seg = tid >> 5;
  float p = 0.f;
  if (a2 < DA) {
    const int kb = seg * 64;
    #pragma unroll 8
    for (int k = 0; k < 64; k++) p = fmaf(ms[kb + k], W1[(kb + k) * DA + a2], p);
  }
  part[seg][a2] = p;
  __syncthreads();
  if (tid < DA) {
    float a = b1[tid];
    #pragma unroll
    for (int s = 0; s < 8; s++) a += part[s][tid];
    as[tid] = tanhf(a);
  }
  __syncthreads();
  if (tid < RR) {
    float s = b2[tid];
    #pragma unroll
    for (int j = 0; j < DA; j++) s = fmaf(as[j], W2[j * RR + tid], s);
    e[row * RR + tid] = __expf(s);
  }
}

// ---------------- K3: per-(b,r) prefix scan -> inv[b,k,r] = 1/cumsum_k e ----------------
__global__ __launch_bounds__(64) void k_scan(const float* __restrict__ e, float* __restrict__ inv) {
  const int b = blockIdx.x / RR, r = blockIdx.x % RR;
  const int lane = threadIdx.x;  // 64
  float v[8];
  float sum = 0.f;
  #pragma unroll
  for (int i = 0; i < 8; i++) { v[i] = e[(b * SS + lane * 8 + i) * RR + r]; sum += v[i]; }
  float inc = sum;
  #pragma unroll
  for (int off = 1; off < 64; off <<= 1) {
    float n = __shfl_up(inc, off);
    if (lane >= off) inc += n;
  }
  float c = inc - sum;  // exclusive prefix
  #pragma unroll
  for (int i = 0; i < 8; i++) { c += v[i]; inv[(b * SS + lane * 8 + i) * RR + r] = 1.0f / c; }
}

// ---------------- K4: attention as streaming scan: M[t,d] = (1/R) sum_r cums(e*m)*inv ----
__global__ __launch_bounds__(128) void k_attn(const __hip_bfloat16* __restrict__ m,
    const float* __restrict__ e, const float* __restrict__ inv, __hip_bfloat16* __restrict__ M) {
  const int b = blockIdx.y;
  const int d = blockIdx.x * 128 + threadIdx.x;
  __shared__ float es[SS * RR];
  __shared__ float is[SS * RR];
  for (int i = threadIdx.x; i < SS * RR; i += 128) {
    es[i] = e[b * SS * RR + i];
    is[i] = inv[b * SS * RR + i];
  }
  __syncthreads();
  float num[RR];
  #pragma unroll
  for (int r = 0; r < RR; r++) num[r] = 0.f;
  const __hip_bfloat16* mb = m + (size_t)b * SS * DD + d;
  __hip_bfloat16* Mb = M + (size_t)b * SS * DD + d;
  #pragma unroll 4
  for (int k = 0; k < SS; k++) {
    const float mv = __bfloat162float(mb[(size_t)k * DD]);
    float acc = 0.f;
    #pragma unroll
    for (int r = 0; r < RR; r++) {
      num[r] = fmaf(es[k * RR + r], mv, num[r]);
      acc = fmaf(num[r], is[k * RR + r], acc);
    }
    Mb[(size_t)k * DD] = __float2bfloat16(acc * (1.0f / RR));
  }
}

// ---------------- K6 v6: persistent GRU — ONE barrier/step, gates fused in dot waves ----
// 256 blocks x 512 thr, 1 block/CU. Block = (batch b, j-slice g of 32 cols), v4 swizzle.
// Thread layout: 16-lane group per jj (32 groups). Lane r = tid&15:
//   r<12:  dot (gate=r>>2 in {r,z,n}, k-quarter q=r&3) — W quarter-row in 16 uint4 VGPRs.
//   r>=12: poller (index p=jj*4+(r-12) in [0,128)) — one sc0 sc1 dwordx4, self-tagged u32s.
// After quad shfl_xor reduce, the 3 gate sums for jj live in lanes B,B+4,B+8 of the SAME
// wave -> two __shfl's to lane r==0, which applies the nonlinearity and stores h directly:
// no second barrier, no gates wave, no gis LDS. Lane r==0 prefetches its 3 gi scalars for
// t+1 right after the store (full step of latency cover).
// WAR safety with ONE barrier: pollers for t+2 (same parity as t) execute only after
// barrier#1(t+1), which all dot lanes reach only after finishing their reads for t.
// h protocol unchanged: u32 fp32-bits, 2-bit mantissa step tag, parity-2 ring.
template<typename GT>
__global__ __launch_bounds__(512) void k_gru(const __hip_bfloat16* __restrict__ WT,
    const GT* __restrict__ gi, const float* __restrict__ bh,
    unsigned int* __restrict__ hslots, void* __restrict__ outv,
    const int* __restrict__ dflag) {
  const int lin = blockIdx.x, tid = threadIdx.x;
  const int xcd = lin & 7, within = lin >> 3;
  const int b = xcd + 8 * (within >> 4);
  const int g = within & 15;                     // j-slice: j in [g*32, g*32+32)
  const int f32o = dflag[0];
  const int jj = tid >> 4;                       // 0..31
  const int r = tid & 15;                        // role within group
  const int gate = r >> 2, q = r & 3;
  const bool isdot = (r < 12);
  const int jg = (g << 5) + jj;                  // global h index of this group
  const int col = (gate << 9) + jg;              // W row (valid for dot lanes)
  __shared__ __align__(16) float hs4[2][4 * 132];   // parity x 4 padded quarters
  // W quarter-row resident in registers: 128 bf16 = 16 uint4 (dot lanes)
  uint4 wr[16];
  if (isdot) {
    const uint4* wp = (const uint4*)(WT + (size_t)col * HH + q * 128);
    #pragma unroll
    for (int i = 0; i < 16; i++) wr[i] = wp[i];
  }
  const float bhr = bh[jg], bhz = bh[512 + jg], bhn = bh[1024 + jg];  // used by r==0
  const int p = (jj << 2) + (r - 12);            // poller uint4 index (r>=12)
  unsigned int* s0 = hslots + b * HH;
  unsigned int* s1 = hslots + BB * HH + b * HH;
  const GT* gib = gi + (size_t)b * SS * G3;
  float gir = 0.f, giz = 0.f, gin = 0.f;
  if (r == 0) {
    gir = ldgi(gib + jg); giz = ldgi(gib + 512 + jg); gin = ldgi(gib + 1024 + jg);
  }

  for (int t = 0; t < SS; t++) {
    const int par = t & 1;
    unsigned int* cur = par ? s1 : s0;
    unsigned int* nxt = par ? s0 : s1;
    if (!isdot) {
      const unsigned want = ((unsigned)t) & 3u;
      const uint4* src = ((const uint4*)cur) + p;
      uint4 v;
      for (;;) {
        asm volatile("global_load_dwordx4 %0, %1, off sc0 sc1\n\ts_waitcnt vmcnt(0)"
                     : "=v"(v) : "v"(src) : "memory");
        if ((v.x & 3u) == want && (v.y & 3u) == want &&
            (v.z & 3u) == want && (v.w & 3u) == want) break;
      }
      float* dq = &hs4[par][(p >> 5) * 132 + ((p << 2) & 127)];
      dq[0] = __uint_as_float(v.x); dq[1] = __uint_as_float(v.y);
      dq[2] = __uint_as_float(v.z); dq[3] = __uint_as_float(v.w);
    }
    __syncthreads();                             // the ONLY barrier per step
    if (isdot) {
      float a0 = 0.f, a1 = 0.f, a2 = 0.f, a3 = 0.f;
      const float4* hp = (const float4*)&hs4[par][q * 132];
      #pragma unroll
      for (int i = 0; i < 16; i++) {
        const uint4 w = wr[i];
        const float4 ha = hp[2 * i];
        const float4 hb = hp[2 * i + 1];
        a0 = fmaf(ha.x, bflo(w.x), a0); a1 = fmaf(ha.y, bfhi(w.x), a1);
        a2 = fmaf(ha.z, bflo(w.y), a2); a3 = fmaf(ha.w, bfhi(w.y), a3);
        a0 = fmaf(hb.x, bflo(w.z), a0); a1 = fmaf(hb.y, bfhi(w.z), a1);
        a2 = fmaf(hb.z, bflo(w.w), a2); a3 = fmaf(hb.w, bfhi(w.w), a3);
      }
      float acc = (a0 + a1) + (a2 + a3);
      acc += __shfl_xor(acc, 1);                 // reduce across q (lane bits 0..1)
      acc += __shfl_xor(acc, 2);
      const int BL = (tid & 63) & ~15;           // group base lane within this wave
      const float sz = __shfl(acc, BL + 4);      // gate z quad-reduced sum
      const float sn = __shfl(acc, BL + 8);      // gate n quad-reduced sum
      if (r == 0) {
        const float ghr = acc + bhr, ghz = sz + bhz, ghn = sn + bhn;
        const float rr = 1.f / (1.f + __expf(-(gir + ghr)));
        const float zz = 1.f / (1.f + __expf(-(giz + ghz)));
        const float nx = gin + rr * ghn;
        const float nn = 1.f - 2.f / (__expf(2.f * nx) + 1.f);   // tanh
        const float hprev = hs4[par][(jg >> 7) * 132 + (jg & 127)];
        const float hnew = nn + zz * (hprev - nn);
        const unsigned pk = (__float_as_uint(hnew) & ~3u) | (((unsigned)(t + 1)) & 3u);
        __hip_atomic_store(nxt + jg, pk, __ATOMIC_RELAXED, __HIP_MEMORY_SCOPE_AGENT);
        const size_t oi = ((size_t)b * SS + t) * HH + jg;
        if (f32o) ((float*)outv)[oi] = hnew;
        else ((__hip_bfloat16*)outv)[oi] = __float2bfloat16(hnew);
        if (t + 1 < SS) {                        // prefetch gi(t+1): full step of cover
          const GT* gn = gib + (size_t)(t + 1) * G3;
          gir = ldgi(gn + jg); giz = ldgi(gn + 512 + jg); gin = ldgi(gn + 1024 + jg);
        }
      }
    }
  }
}

extern "C" void kernel_launch(void* const* d_in, const int* in_sizes, int n_in,
                              void* d_out, int out_size, void* d_ws, size_t ws_size,
                              hipStream_t stream) {
  char* wsb = (char*)d_ws;
  unsigned int* hslots = (unsigned int*)(wsb + OFF_H);
  int* dflag  = (int*)(wsb + OFF_DF);
  float* cx   = (float*)(wsb + OFF_CX);
  float* cW0  = (float*)(wsb + OFF_CW0);
  float* cb0  = (float*)(wsb + OFF_CB0);
  float* cW1  = (float*)(wsb + OFF_CW1);
  float* cb1  = (float*)(wsb + OFF_CB1);
  float* cW2  = (float*)(wsb + OFF_CW2);
  float* cb2  = (float*)(wsb + OFF_CB2);
  float* cWih = (float*)(wsb + OFF_CWIH);
  float* cWhh = (float*)(wsb + OFF_CWHH);
  float* cbi  = (float*)(wsb + OFF_CBI);
  float* cbh  = (float*)(wsb + OFF_CBH);
  __hip_bfloat16* WT   = (__hip_bfloat16*)(wsb + OFF_WT);
  __hip_bfloat16* WihT = (__hip_bfloat16*)(wsb + OFF_WIHT);
  __hip_bfloat16* W0T  = (__hip_bfloat16*)(wsb + OFF_W0T);
  __hip_bfloat16* Mm   = (__hip_bfloat16*)(wsb + OFF_MM);
  __hip_bfloat16* m    = (__hip_bfloat16*)(wsb + OFF_M);
  float* e   = (float*)(wsb + OFF_E);
  float* inv = (float*)(wsb + OFF_INV);
  void* gip  = (void*)(wsb + OFF_GI);
  const bool gi32 = (ws_size >= NEED_GI32);   // constant across calls -> same work every call

  // k_detect zeroes the h ring (ws is poisoned 0xAA before every call) and sets dflag
  k_detect<<<1, 256, 0, stream>>>((const unsigned short*)d_in[0], dflag, (uint4*)hslots);

  CvtArgs ca;
  float* dsts[11] = {cx, cW0, cb0, cW1, cb1, cW2, cb2, cWih, cWhh, cbi, cbh};
  const int ns[11] = {BB * SS * IN_, IN_ * DD, DD, DD * DA, DA, DA * RR, RR,
                      DD * G3, HH * G3, G3, G3};
  for (int i = 0; i < 11; i++) { ca.src[i] = d_in[i]; ca.dst[i] = dsts[i]; ca.n[i] = ns[i]; }
  k_cvt<<<dim3(128, 11), 256, 0, stream>>>(ca, dflag);

  k_transpose3<<<1600, dim3(32, 32), 0, stream>>>(cWhh, cWih, cW0, WT, WihT, W0T);
  // m = relu(x @ W0 + b0) via MFMA (fp32 A staged to bf16)
  k_gemm<float, __hip_bfloat16, IN_, true>
      <<<dim3(DD / 128, (BB * SS) / 128), 256, 0, stream>>>(cx, W0T, cb0, m, DD);
  k_scores<<<BB * SS, 256, 0, stream>>>(m, cW1, cb1, cW2, cb2, e);
  k_scan<<<BB * RR, 64, 0, stream>>>(e, inv);
  k_attn<<<dim3(4, BB), 128, 0, stream>>>(m, e, inv, Mm);
  if (gi32) {
    k_gemm<__hip_bfloat16, float, DD, false>
        <<<dim3(G3 / 128, (BB * SS) / 128), 256, 0, stream>>>(Mm, WihT, cbi, (float*)gip, G3);
    k_gru<float><<<256, 512, 0, stream>>>(WT, (const float*)gip, cbh, hslots, d_out, dflag);
  } else {
    k_gemm<__hip_bfloat16, __hip_bfloat16, DD, false>
        <<<dim3(G3 / 128, (BB * SS) / 128), 256, 0, stream>>>(Mm, WihT, cbi,
                                                              (__hip_bfloat16*)gip, G3);
    k_gru<__hip_bfloat16><<<256, 512, 0, stream>>>(WT, (const __hip_bfloat16*)gip, cbh,
                                                   hslots, d_out, dflag);
  }
}

// Round 12
// 1194.590 us; speedup vs baseline: 1.4442x; 1.4442x over previous
//
#include <hip/hip_runtime.h>
#include <hip/hip_bf16.h>

// Problem dims
#define BB 16
#define SS 512
#define IN_ 128
#define DD 512
#define HH 512
#define DA 30
#define RR 10
#define G3 1536   // 3*H

// ---- ws layout (bytes) ----
constexpr size_t OFF_H    = 0;                        // tagged h ring u32[2][16][512]: 65,536
constexpr size_t OFF_DF   = 131072;                   // dtype flag: 256
constexpr size_t OFF_CX   = OFF_DF   + 256;           // canonical fp32 inputs
constexpr size_t OFF_CW0  = OFF_CX   + 4194304;
constexpr size_t OFF_CB0  = OFF_CW0  + 262144;
constexpr size_t OFF_CW1  = OFF_CB0  + 2048;
constexpr size_t OFF_CB1  = OFF_CW1  + 61440;
constexpr size_t OFF_CW2  = OFF_CB1  + 256;
constexpr size_t OFF_CB2  = OFF_CW2  + 2048;
constexpr size_t OFF_CWIH = OFF_CB2  + 256;
constexpr size_t OFF_CWHH = OFF_CWIH + 3145728;
constexpr size_t OFF_CBI  = OFF_CWHH + 3145728;
constexpr size_t OFF_CBH  = OFF_CBI  + 6144;
constexpr size_t OFF_WT   = OFF_CBH  + 6144;          // W_hh^T bf16 [1536][512]
constexpr size_t OFF_WIHT = OFF_WT   + 1572864;       // W_ih^T bf16 [1536][512]
constexpr size_t OFF_W0T  = OFF_WIHT + 1572864;       // W0^T bf16 [512][128]
constexpr size_t OFF_MM   = OFF_W0T  + 131072;        // M bf16 [8192][512]
constexpr size_t OFF_BIG  = OFF_MM   + 8388608;
constexpr size_t OFF_M    = OFF_BIG;                  // m bf16 [8192][512]
constexpr size_t OFF_E    = OFF_BIG  + 8388608;       // e f32 [8192][10]
constexpr size_t OFF_INV  = OFF_E    + 327680;        // inv f32
constexpr size_t OFF_GI   = OFF_BIG;                  // gi aliases m/e/inv (dead after k_attn)
constexpr size_t NEED_GI32 = OFF_BIG + 50331648;      // gi fp32 path total

typedef __attribute__((ext_vector_type(8))) short bf16x8;
typedef __attribute__((ext_vector_type(4))) float f32x4;

__device__ __forceinline__ float bflo(unsigned int u) { return __uint_as_float(u << 16); }
__device__ __forceinline__ float bfhi(unsigned int u) { return __uint_as_float(u & 0xffff0000u); }
__device__ __forceinline__ float bf1(unsigned short u) { return __uint_as_float(((unsigned int)u) << 16); }
__device__ __forceinline__ unsigned short f2b(float f) {
  __hip_bfloat16 h = __float2bfloat16(f);
  return *(unsigned short*)&h;
}

__device__ __forceinline__ float ldgi(const float* p) { return *p; }
__device__ __forceinline__ float ldgi(const __hip_bfloat16* p) { return __bfloat162float(*p); }
__device__ __forceinline__ void stgi(float* p, float v) { *p = v; }
__device__ __forceinline__ void stgi(__hip_bfloat16* p, float v) { *p = __float2bfloat16(v); }

// ---------------- K0a: detect input dtype + zero the h ring ----------------
__global__ __launch_bounds__(256) void k_detect(const unsigned short* __restrict__ xs,
                                                int* __restrict__ dflag,
                                                uint4* __restrict__ hz) {
  const int tid = threadIdx.x;
  // zero tagged h ring: 65,536 B = 4096 uint4 (bits 0 == h=0.0 with tag 0)
  const uint4 z = {0u, 0u, 0u, 0u};
  #pragma unroll
  for (int i = 0; i < 16; i++) hz[tid + i * 256] = z;
  int bad = 0;
  for (int i = tid; i < 8192; i += 256) {
    const float v = bf1(xs[i]);
    if (!(fabsf(v) < 1.0e3f)) bad++;   // NaN also counts
  }
  __shared__ int s;
  if (tid == 0) s = 0;
  __syncthreads();
  atomicAdd(&s, bad);
  __syncthreads();
  if (tid == 0) dflag[0] = (s > 16) ? 1 : 0;   // 1 = fp32 buffers, 0 = bf16 buffers
}

// ---------------- K0b: canonicalize all inputs to fp32 ----------------
struct CvtArgs { const void* src[11]; float* dst[11]; int n[11]; };
__global__ __launch_bounds__(256) void k_cvt(CvtArgs a, const int* __restrict__ dflag) {
  const int ai = blockIdx.y;
  const int n = a.n[ai];
  const int stride = gridDim.x * blockDim.x;
  const int f32 = dflag[0];
  float* dst = a.dst[ai];
  if (f32) {
    const float* src = (const float*)a.src[ai];
    for (int i = blockIdx.x * blockDim.x + threadIdx.x; i < n; i += stride) dst[i] = src[i];
  } else {
    const unsigned short* src = (const unsigned short*)a.src[ai];
    for (int i = blockIdx.x * blockDim.x + threadIdx.x; i < n; i += stride) dst[i] = bf1(src[i]);
  }
}

// ---------------- K1: fused transpose of W_hh, W_ih (512x1536) and W0 (128x512) ------
__global__ __launch_bounds__(1024) void k_transpose3(const float* __restrict__ Whh,
    const float* __restrict__ Wih, const float* __restrict__ W0,
    __hip_bfloat16* __restrict__ WhhT, __hip_bfloat16* __restrict__ WihT,
    __hip_bfloat16* __restrict__ W0T) {
  __shared__ float tile[32][33];
  int id = blockIdx.x;
  const float* W; __hip_bfloat16* WT; int R, C, tx, ty;
  if (id < 768)       { W = Whh; WT = WhhT; R = DD;  C = G3; tx = id % 48; ty = id / 48; }
  else if (id < 1536) { id -= 768;  W = Wih; WT = WihT; R = DD;  C = G3; tx = id % 48; ty = id / 48; }
  else                { id -= 1536; W = W0;  WT = W0T;  R = IN_; C = DD; tx = id % 16; ty = id / 16; }
  const int c0 = tx * 32, k0 = ty * 32;
  tile[threadIdx.y][threadIdx.x] = W[(k0 + threadIdx.y) * C + c0 + threadIdx.x];
  __syncthreads();
  WT[(c0 + threadIdx.y) * R + k0 + threadIdx.x] = __float2bfloat16(tile[threadIdx.x][threadIdx.y]);
}

// ---------------- K5: unified MFMA GEMM: C[M][N] = A[M][KD] @ Bt[N][KD]^T + bias ------
// Tile 128x128, 4 waves (2x2 of 64x64), BK=32. A staged fp32->bf16 or bf16 direct.
// C/D frag: col=lane&15, row=quad*4+reg (m89-verified).
template<typename AT, typename GT, int KD, bool RELU>
__global__ __launch_bounds__(256) void k_gemm(const AT* __restrict__ A,
    const __hip_bfloat16* __restrict__ Bt, const float* __restrict__ bias,
    GT* __restrict__ C, int ldc) {
  __shared__ short As[128 * 40];   // 128 rows x 32 k, stride 40 (bank de-phase)
  __shared__ short Bs[128 * 40];
  const int tid = threadIdx.x;
  const int bn = blockIdx.x * 128, bm = blockIdx.y * 128;
  const int lane = tid & 63, w = tid >> 6;
  const int wm = (w >> 1) * 64, wn = (w & 1) * 64;
  const int l15 = lane & 15, quad = lane >> 4;
  const int srow = tid >> 1, shalf = tid & 1;    // staging: row, 16-elem half of 32-chunk
  f32x4 acc[4][4];
  #pragma unroll
  for (int i = 0; i < 4; i++)
    #pragma unroll
    for (int j = 0; j < 4; j++) acc[i][j] = (f32x4){0.f, 0.f, 0.f, 0.f};
  const uint4* Bg = (const uint4*)(Bt + (size_t)(bn + srow) * KD);
  short* Asd = &As[srow * 40 + shalf * 16];
  short* Bsd = &Bs[srow * 40 + shalf * 16];
  #pragma unroll 2
  for (int kc = 0; kc < KD / 32; kc++) {
    if constexpr (sizeof(AT) == 4) {   // fp32 A: 16 floats -> 16 bf16
      const float4* Agf = (const float4*)(A + (size_t)(bm + srow) * KD) + kc * 8 + shalf * 4;
      const float4 f0 = Agf[0], f1 = Agf[1], f2 = Agf[2], f3 = Agf[3];
      unsigned short t16[16] = {
        f2b(f0.x), f2b(f0.y), f2b(f0.z), f2b(f0.w),
        f2b(f1.x), f2b(f1.y), f2b(f1.z), f2b(f1.w),
        f2b(f2.x), f2b(f2.y), f2b(f2.z), f2b(f2.w),
        f2b(f3.x), f2b(f3.y), f2b(f3.z), f2b(f3.w)};
      *(uint4*)&Asd[0] = *(uint4*)&t16[0];
      *(uint4*)&Asd[8] = *(uint4*)&t16[8];
    } else {                            // bf16 A
      const uint4* Ag = (const uint4*)(A + (size_t)(bm + srow) * KD);
      const uint4 a0 = Ag[kc * 4 + shalf * 2], a1 = Ag[kc * 4 + shalf * 2 + 1];
      *(uint4*)&Asd[0] = a0; *(uint4*)&Asd[8] = a1;
    }
    const uint4 b0 = Bg[kc * 4 + shalf * 2], b1 = Bg[kc * 4 + shalf * 2 + 1];
    *(uint4*)&Bsd[0] = b0; *(uint4*)&Bsd[8] = b1;
    __syncthreads();
    bf16x8 af[4], bf[4];
    #pragma unroll
    for (int tt = 0; tt < 4; tt++) {
      af[tt] = *(const bf16x8*)&As[(wm + tt * 16 + l15) * 40 + quad * 8];
      bf[tt] = *(const bf16x8*)&Bs[(wn + tt * 16 + l15) * 40 + quad * 8];
    }
    #pragma unroll
    for (int tm = 0; tm < 4; tm++)
      #pragma unroll
      for (int tn = 0; tn < 4; tn++)
        acc[tm][tn] = __builtin_amdgcn_mfma_f32_16x16x32_bf16(af[tm], bf[tn], acc[tm][tn], 0, 0, 0);
    __syncthreads();
  }
  #pragma unroll
  for (int tn = 0; tn < 4; tn++) {
    const int col = bn + wn + tn * 16 + l15;
    const float bv = bias[col];
    #pragma unroll
    for (int tm = 0; tm < 4; tm++) {
      const int row = bm + wm + tm * 16 + quad * 4;
      #pragma unroll
      for (int i = 0; i < 4; i++) {
        float v = acc[tm][tn][i] + bv;
        if constexpr (RELU) v = fmaxf(v, 0.f);
        stgi(C + (size_t)(row + i) * ldc + col, v);
      }
    }
  }
}

// ---------------- K2b: scores per row: e = exp(tanh(m@W1+b1)@W2+b2) ----------------
__global__ __launch_bounds__(256) void k_scores(const __hip_bfloat16* __restrict__ m,
    const float* __restrict__ W1, const float* __restrict__ b1,
    const float* __restrict__ W2, const float* __restrict__ b2,
    float* __restrict__ e) {
  const int row = blockIdx.x;        // b*512+s
  const int tid = threadIdx.x;       // 256
  __shared__ float ms[DD];
  __shared__ float as[DA];
  __shared__ float part[8][32];
  {
    const unsigned int mm = ((const unsigned int*)(m + (size_t)row * DD))[tid];
    ms[2 * tid] = bflo(mm); ms[2 * tid + 1] = bfhi(mm);
  }
  __syncthreads();
  // m@W1: seg-split over k — all 256 threads active (a2<30 lanes idle only)
  const int a2 = tid & 31, seg = tid >> 5;
  float p = 0.f;
  if (a2 < DA) {
    const int kb = seg * 64;
    #pragma unroll 8
    for (int k = 0; k < 64; k++) p = fmaf(ms[kb + k], W1[(kb + k) * DA + a2], p);
  }
  part[seg][a2] = p;
  __syncthreads();
  if (tid < DA) {
    float a = b1[tid];
    #pragma unroll
    for (int s = 0; s < 8; s++) a += part[s][tid];
    as[tid] = tanhf(a);
  }
  __syncthreads();
  if (tid < RR) {
    float s = b2[tid];
    #pragma unroll
    for (int j = 0; j < DA; j++) s = fmaf(as[j], W2[j * RR + tid], s);
    e[row * RR + tid] = __expf(s);
  }
}

// ---------------- K3: per-(b,r) prefix scan -> inv[b,k,r] = 1/cumsum_k e ----------------
__global__ __launch_bounds__(64) void k_scan(const float* __restrict__ e, float* __restrict__ inv) {
  const int b = blockIdx.x / RR, r = blockIdx.x % RR;
  const int lane = threadIdx.x;  // 64
  float v[8];
  float sum = 0.f;
  #pragma unroll
  for (int i = 0; i < 8; i++) { v[i] = e[(b * SS + lane * 8 + i) * RR + r]; sum += v[i]; }
  float inc = sum;
  #pragma unroll
  for (int off = 1; off < 64; off <<= 1) {
    float n = __shfl_up(inc, off);
    if (lane >= off) inc += n;
  }
  float c = inc - sum;  // exclusive prefix
  #pragma unroll
  for (int i = 0; i < 8; i++) { c += v[i]; inv[(b * SS + lane * 8 + i) * RR + r] = 1.0f / c; }
}

// ---------------- K4: attention as streaming scan: M[t,d] = (1/R) sum_r cums(e*m)*inv ----
__global__ __launch_bounds__(128) void k_attn(const __hip_bfloat16* __restrict__ m,
    const float* __restrict__ e, const float* __restrict__ inv, __hip_bfloat16* __restrict__ M) {
  const int b = blockIdx.y;
  const int d = blockIdx.x * 128 + threadIdx.x;
  __shared__ float es[SS * RR];
  __shared__ float is[SS * RR];
  for (int i = threadIdx.x; i < SS * RR; i += 128) {
    es[i] = e[b * SS * RR + i];
    is[i] = inv[b * SS * RR + i];
  }
  __syncthreads();
  float num[RR];
  #pragma unroll
  for (int r = 0; r < RR; r++) num[r] = 0.f;
  const __hip_bfloat16* mb = m + (size_t)b * SS * DD + d;
  __hip_bfloat16* Mb = M + (size_t)b * SS * DD + d;
  #pragma unroll 4
  for (int k = 0; k < SS; k++) {
    const float mv = __bfloat162float(mb[(size_t)k * DD]);
    float acc = 0.f;
    #pragma unroll
    for (int r = 0; r < RR; r++) {
      num[r] = fmaf(es[k * RR + r], mv, num[r]);
      acc = fmaf(num[r], is[k * RR + r], acc);
    }
    Mb[(size_t)k * DD] = __float2bfloat16(acc * (1.0f / RR));
  }
}

// ---------------- K6 v4 (proven, rounds 8/10): persistent GRU — 16 blocks/batch --------
// 256 blocks x 384 thr, 1 block/CU. Block = (batch b, j-slice g of 32 cols). Swizzle:
// lin = b%8 + 8*(g + 16*(b/8)) -> all 16 blocks of a batch on one XCD (heuristic only).
// W rows (96 x 512) in VGPRs: thread (c<96, q<4) holds 128 bf16 (16 uint4).
// h = u32 fp32-bits with 2-bit mantissa step-tag (tear-proof), parity-2 ring.
// Poll: tid<128, ONE dwordx4 sc0 sc1 per sweep (4 self-tagged dwords). hs4/gis parity
// double-buffered in LDS -> 2 barriers/step. Gates on dedicated wave (tid 352..383) ->
// coalesced h/out stores from a single wave. gi prefetch on tid 256..351.
// LESSONS (r9/r11): do NOT pair batches per block (serializes RTT chain); do NOT fuse
// gates into dot waves (scatters stores, puts pollers in every wave).
template<typename GT>
__global__ __launch_bounds__(384) void k_gru(const __hip_bfloat16* __restrict__ WT,
    const GT* __restrict__ gi, const float* __restrict__ bh,
    unsigned int* __restrict__ hslots, void* __restrict__ outv,
    const int* __restrict__ dflag) {
  const int lin = blockIdx.x, tid = threadIdx.x;
  const int xcd = lin & 7, within = lin >> 3;
  const int b = xcd + 8 * (within >> 4);
  const int g = within & 15;                     // j-slice: j in [g*32, g*32+32)
  const int f32o = dflag[0];
  const int c = tid >> 2, q = tid & 3;           // row c<96 (= gate*32+jj), k-quarter q<4
  const int col = ((c >> 5) << 9) + (g << 5) + (c & 31);
  __shared__ __align__(16) float hs4[2][4 * 132];   // parity x 4 padded quarters
  __shared__ float ghs[96];
  __shared__ float gis[2][96];
  // W quarter-row resident in registers: 128 bf16 = 16 uint4 (64 VGPRs)
  uint4 wr[16];
  {
    const uint4* wp = (const uint4*)(WT + (size_t)col * HH + q * 128);
    #pragma unroll
    for (int i = 0; i < 16; i++) wr[i] = wp[i];
  }
  const float bias_c = bh[col];
  // gi prefetch threads: tid in [256,352) <-> slot 0..95
  const int pslot = tid - 256;
  const bool pf = (pslot >= 0 && pslot < 96);
  const int gcol = pf ? (((pslot >> 5) << 9) + (g << 5) + (pslot & 31)) : 0;
  // gates threads: tid in [352,384) <-> jj 0..31
  const bool gt = (tid >= 352);
  const int jj = tid - 352;
  const int jg = (g << 5) + jj;
  unsigned int* s0 = hslots + b * HH;
  unsigned int* s1 = hslots + BB * HH + b * HH;
  const GT* gib = gi + (size_t)b * SS * G3;
  float gpre = pf ? ldgi(gib + gcol) : 0.f;

  for (int t = 0; t < SS; t++) {
    const int par = t & 1;
    unsigned int* cur = par ? s1 : s0;
    unsigned int* nxt = par ? s0 : s1;
    // poll+stage h_t: tid<128 polls one uint4 (slots 4tid..4tid+3, same quarter)
    if (tid < 128) {
      const unsigned want = ((unsigned)t) & 3u;
      const uint4* src = ((const uint4*)cur) + tid;
      uint4 v;
      for (;;) {
        asm volatile("global_load_dwordx4 %0, %1, off sc0 sc1\n\ts_waitcnt vmcnt(0)"
                     : "=v"(v) : "v"(src) : "memory");
        if ((v.x & 3u) == want && (v.y & 3u) == want &&
            (v.z & 3u) == want && (v.w & 3u) == want) break;
      }
      float* dq = &hs4[par][(tid >> 5) * 132 + ((tid * 4) & 127)];
      dq[0] = __uint_as_float(v.x); dq[1] = __uint_as_float(v.y);
      dq[2] = __uint_as_float(v.z); dq[3] = __uint_as_float(v.w);
    }
    if (pf) gis[par][pslot] = gpre;
    __syncthreads();                                    // #1 (stage -> dot)
    if (pf && t + 1 < SS) gpre = ldgi(gib + (size_t)(t + 1) * G3 + gcol);  // overlap dot
    // dot: row col, k in [q*128, q*128+128)
    float a0 = 0.f, a1 = 0.f, a2 = 0.f, a3 = 0.f;
    const float4* hp = (const float4*)&hs4[par][q * 132];
    #pragma unroll
    for (int i = 0; i < 16; i++) {
      const uint4 w = wr[i];
      const float4 ha = hp[2 * i];
      const float4 hb = hp[2 * i + 1];
      a0 = fmaf(ha.x, bflo(w.x), a0); a1 = fmaf(ha.y, bfhi(w.x), a1);
      a2 = fmaf(ha.z, bflo(w.y), a2); a3 = fmaf(ha.w, bfhi(w.y), a3);
      a0 = fmaf(hb.x, bflo(w.z), a0); a1 = fmaf(hb.y, bfhi(w.z), a1);
      a2 = fmaf(hb.z, bflo(w.w), a2); a3 = fmaf(hb.w, bfhi(w.w), a3);
    }
    float acc = (a0 + a1) + (a2 + a3);
    acc += __shfl_xor(acc, 1);   // reduce across q (lane bits 0..1)
    acc += __shfl_xor(acc, 2);
    if (q == 0) ghs[c] = acc + bias_c;
    __syncthreads();                                    // #2 (ghs/gis -> gates; hs4 WAR)
    if (gt) {
      const float ghr = ghs[jj], ghz = ghs[32 + jj], ghn = ghs[64 + jj];
      const float gir = gis[par][jj], giz = gis[par][32 + jj], gin = gis[par][64 + jj];
      const float r = 1.f / (1.f + __expf(-(gir + ghr)));
      const float z = 1.f / (1.f + __expf(-(giz + ghz)));
      const float nx = gin + r * ghn;
      const float n = 1.f - 2.f / (__expf(2.f * nx) + 1.f);   // tanh
      const float hprev = hs4[par][(jg >> 7) * 132 + (jg & 127)];
      const float hnew = n + z * (hprev - n);
      const unsigned pk = (__float_as_uint(hnew) & ~3u) | (((unsigned)(t + 1)) & 3u);
      __hip_atomic_store(nxt + jg, pk, __ATOMIC_RELAXED, __HIP_MEMORY_SCOPE_AGENT);
      const size_t oi = ((size_t)b * SS + t) * HH + jg;
      if (f32o) ((float*)outv)[oi] = hnew;
      else ((__hip_bfloat16*)outv)[oi] = __float2bfloat16(hnew);
    }
    // no barrier #3: hs4/gis parity double-buffered; ghs WAR fenced by barrier #1
  }
}

extern "C" void kernel_launch(void* const* d_in, const int* in_sizes, int n_in,
                              void* d_out, int out_size, void* d_ws, size_t ws_size,
                              hipStream_t stream) {
  char* wsb = (char*)d_ws;
  unsigned int* hslots = (unsigned int*)(wsb + OFF_H);
  int* dflag  = (int*)(wsb + OFF_DF);
  float* cx   = (float*)(wsb + OFF_CX);
  float* cW0  = (float*)(wsb + OFF_CW0);
  float* cb0  = (float*)(wsb + OFF_CB0);
  float* cW1  = (float*)(wsb + OFF_CW1);
  float* cb1  = (float*)(wsb + OFF_CB1);
  float* cW2  = (float*)(wsb + OFF_CW2);
  float* cb2  = (float*)(wsb + OFF_CB2);
  float* cWih = (float*)(wsb + OFF_CWIH);
  float* cWhh = (float*)(wsb + OFF_CWHH);
  float* cbi  = (float*)(wsb + OFF_CBI);
  float* cbh  = (float*)(wsb + OFF_CBH);
  __hip_bfloat16* WT   = (__hip_bfloat16*)(wsb + OFF_WT);
  __hip_bfloat16* WihT = (__hip_bfloat16*)(wsb + OFF_WIHT);
  __hip_bfloat16* W0T  = (__hip_bfloat16*)(wsb + OFF_W0T);
  __hip_bfloat16* Mm   = (__hip_bfloat16*)(wsb + OFF_MM);
  __hip_bfloat16* m    = (__hip_bfloat16*)(wsb + OFF_M);
  float* e   = (float*)(wsb + OFF_E);
  float* inv = (float*)(wsb + OFF_INV);
  void* gip  = (void*)(wsb + OFF_GI);
  const bool gi32 = (ws_size >= NEED_GI32);   // constant across calls -> same work every call

  // k_detect zeroes the h ring (ws is poisoned 0xAA before every call) and sets dflag
  k_detect<<<1, 256, 0, stream>>>((const unsigned short*)d_in[0], dflag, (uint4*)hslots);

  CvtArgs ca;
  float* dsts[11] = {cx, cW0, cb0, cW1, cb1, cW2, cb2, cWih, cWhh, cbi, cbh};
  const int ns[11] = {BB * SS * IN_, IN_ * DD, DD, DD * DA, DA, DA * RR, RR,
                      DD * G3, HH * G3, G3, G3};
  for (int i = 0; i < 11; i++) { ca.src[i] = d_in[i]; ca.dst[i] = dsts[i]; ca.n[i] = ns[i]; }
  k_cvt<<<dim3(128, 11), 256, 0, stream>>>(ca, dflag);

  k_transpose3<<<1600, dim3(32, 32), 0, stream>>>(cWhh, cWih, cW0, WT, WihT, W0T);
  // m = relu(x @ W0 + b0) via MFMA (fp32 A staged to bf16)
  k_gemm<float, __hip_bfloat16, IN_, true>
      <<<dim3(DD / 128, (BB * SS) / 128), 256, 0, stream>>>(cx, W0T, cb0, m, DD);
  k_scores<<<BB * SS, 256, 0, stream>>>(m, cW1, cb1, cW2, cb2, e);
  k_scan<<<BB * RR, 64, 0, stream>>>(e, inv);
  k_attn<<<dim3(4, BB), 128, 0, stream>>>(m, e, inv, Mm);
  if (gi32) {
    k_gemm<__hip_bfloat16, float, DD, false>
        <<<dim3(G3 / 128, (BB * SS) / 128), 256, 0, stream>>>(Mm, WihT, cbi, (float*)gip, G3);
    k_gru<float><<<256, 384, 0, stream>>>(WT, (const float*)gip, cbh, hslots, d_out, dflag);
  } else {
    k_gemm<__hip_bfloat16, __hip_bfloat16, DD, false>
        <<<dim3(G3 / 128, (BB * SS) / 128), 256, 0, stream>>>(Mm, WihT, cbi,
                                                              (__hip_bfloat16*)gip, G3);
    k_gru<__hip_bfloat16><<<256, 384, 0, stream>>>(WT, (const __hip_bfloat16*)gip, cbh,
                                                   hslots, d_out, dflag);
  }
}